// Round 14
// baseline (204.048 us; speedup 1.0000x reference)
//
#include <hip/hip_runtime.h>
#include <hip/hip_bf16.h>
#include <math.h>

typedef __bf16 bf16_t;
typedef __bf16 bf16x8 __attribute__((ext_vector_type(8)));
typedef __bf16 bf16x4 __attribute__((ext_vector_type(4)));
typedef float  f32x4  __attribute__((ext_vector_type(4)));

#define L_DIM 2048
#define D_DIM 1024
#define H_DIM 16
#define M_DIM 4096
#define KTOP 409
#define SLOTS 512      // sel padding (128-slot q-chunks; sel = -1 beyond KTOP)
#define SLOTS_IO 448   // Oo/Ol stride (real slots < 448) — keeps 16MB window
#define KSPLIT 8
#define KCHUNK 256     // L_DIM / KSPLIT
#define HSZ (L_DIM * 64)   // elements per (b,h) head block = 131072

// split f32 into bf16 hi + bf16 lo (a ~= hi + lo)
__device__ __forceinline__ void split2(float a, bf16_t& h, bf16_t& l) {
  h = (bf16_t)a;
  l = (bf16_t)(a - (float)h);
}

// async global -> LDS, 16B per lane; lds ptr must be wave-uniform (m104/m108)
__device__ __forceinline__ void gld16(const bf16_t* g, bf16_t* l) {
  __builtin_amdgcn_global_load_lds(
      (const __attribute__((address_space(1))) void*)g,
      (__attribute__((address_space(3))) void*)l, 16, 0, 0);
}

// LDS source-side XOR swizzle (rule #21; perf-neutral measured, kept)
#define STAGE_TILE128(src, dst)                                               \
  {                                                                           \
    const int seg0 = wave * 2;                                                \
    const int r0 = seg0 * 16 + (lane >> 2);                                   \
    const int c0 = (((lane & 3) ^ ((lane >> 2) & 3))) * 8;                    \
    gld16((src) + (size_t)r0 * D_DIM + c0, (dst) + seg0 * 512);               \
    gld16((src) + (size_t)(r0 + 16) * D_DIM + c0, (dst) + (seg0 + 1) * 512);  \
  }

#define STAGE_TILE64(src, dst)                                                \
  {                                                                           \
    const int r0 = wave * 16 + (lane >> 2);                                   \
    const int c0 = (((lane & 3) ^ ((lane >> 2) & 3))) * 8;                    \
    gld16((src) + (size_t)r0 * D_DIM + c0, (dst) + wave * 512);               \
  }

#define FRAG(buf, ROW) \
  (*reinterpret_cast<const bf16x8*>(&(buf)[(ROW) * 32 + (quad ^ (lm & 3)) * 8]))

// ---------------------------------------------------------------------------
// prep: pre-split x and Wq into bf16 hi/lo; pre-round Wk/Wv/Wo to bf16.
// Also zeroes the Vmean accumulator (2048 f32 = 512 f32x4 items).
// ---------------------------------------------------------------------------
__global__ __launch_bounds__(256) void prep_kernel(
    const float* __restrict__ x,  const float* __restrict__ Wq,
    const float* __restrict__ Wk, const float* __restrict__ Wv,
    const float* __restrict__ Wo,
    bf16_t* __restrict__ xhi, bf16_t* __restrict__ xlo,
    bf16_t* __restrict__ Wqhi, bf16_t* __restrict__ Wqlo,
    bf16_t* __restrict__ Wkb,  bf16_t* __restrict__ Wvb,
    bf16_t* __restrict__ Wob,  float* __restrict__ Vmeanf)
{
  const int XV = (M_DIM * D_DIM) / 4;
  const int WV = (D_DIM * D_DIM) / 4;
  const int TOT = XV + 4 * WV + 512;
  for (int i = blockIdx.x * 256 + threadIdx.x; i < TOT; i += gridDim.x * 256) {
    if (i < XV) {
      f32x4 v = ((const f32x4*)x)[i];
      bf16x4 h, l;
      #pragma unroll
      for (int j = 0; j < 4; ++j) { bf16_t hh, ll; split2(v[j], hh, ll); h[j] = hh; l[j] = ll; }
      ((bf16x4*)xhi)[i] = h;
      ((bf16x4*)xlo)[i] = l;
    } else if (i < XV + WV) {
      int j0 = i - XV;
      f32x4 v = ((const f32x4*)Wq)[j0];
      bf16x4 h, l;
      #pragma unroll
      for (int j = 0; j < 4; ++j) { bf16_t hh, ll; split2(v[j], hh, ll); h[j] = hh; l[j] = ll; }
      ((bf16x4*)Wqhi)[j0] = h;
      ((bf16x4*)Wqlo)[j0] = l;
    } else if (i < XV + 2 * WV) {
      int j0 = i - XV - WV;
      f32x4 v = ((const f32x4*)Wk)[j0];
      bf16x4 h;
      #pragma unroll
      for (int j = 0; j < 4; ++j) h[j] = (bf16_t)v[j];
      ((bf16x4*)Wkb)[j0] = h;
    } else if (i < XV + 3 * WV) {
      int j0 = i - XV - 2 * WV;
      f32x4 v = ((const f32x4*)Wv)[j0];
      bf16x4 h;
      #pragma unroll
      for (int j = 0; j < 4; ++j) h[j] = (bf16_t)v[j];
      ((bf16x4*)Wvb)[j0] = h;
    } else if (i < XV + 4 * WV) {
      int j0 = i - XV - 3 * WV;
      f32x4 v = ((const f32x4*)Wo)[j0];
      bf16x4 h;
      #pragma unroll
      for (int j = 0; j < 4; ++j) h[j] = (bf16_t)v[j];
      ((bf16x4*)Wob)[j0] = h;
    } else {
      int j0 = i - XV - 4 * WV;           // 0..511
      f32x4 zz = {0.f, 0.f, 0.f, 0.f};
      ((f32x4*)Vmeanf)[j0] = zz;
    }
  }
}

// ---------------------------------------------------------------------------
// Fused QKV projections — r5 structure (measured best, 3 blocks/CU).
// z0 split into A/B phases at 48 KB LDS, prefetch dbuf.
// K written per-head [b][h][L][64]; V key-tiled [(b,h)][kb][d][32].
// z2 epilogue accumulates column-sums of V into Vmeanf (f32 atomics).
// ---------------------------------------------------------------------------
__global__ __launch_bounds__(256, 3) void gemm_qkv(
    const bf16_t* __restrict__ xhi, const bf16_t* __restrict__ xlo,
    const bf16_t* __restrict__ Wqhi, const bf16_t* __restrict__ Wqlo,
    const bf16_t* __restrict__ Wkb, const bf16_t* __restrict__ Wvb,
    const float* __restrict__ bq, const float* __restrict__ bk, const float* __restrict__ bv,
    bf16_t* __restrict__ Qhi, bf16_t* __restrict__ Khi, bf16_t* __restrict__ VThi,
    float* __restrict__ norms, float* __restrict__ Vmeanf)
{
  const int bx = blockIdx.x;
  const int z  = bx % 3;          // interleaved so each CU gets a z-mix
  const int id = bx / 3;          // 0..255
  const int n0   = (id & 7) * 128;
  const int row0 = (id >> 3) * 128;

  __shared__ __align__(16) bf16_t sm[2][3][4096];   // 48 KB: dbuf x 3 tiles

  const int tid  = threadIdx.x;
  const int lane = tid & 63;
  const int wave = tid >> 6;
  const int wr = wave >> 1, wc = wave & 1;
  const int lm = lane & 15, quad = lane >> 4;

  const f32x4 vzero = {0.f, 0.f, 0.f, 0.f};
  f32x4 acc[4][4];
  #pragma unroll
  for (int mi = 0; mi < 4; ++mi)
    #pragma unroll
    for (int ni = 0; ni < 4; ++ni) acc[mi][ni] = vzero;

  if (z == 0) {
#define STAGE_A(k0, b) do {                                                  \
      STAGE_TILE128(xhi  + (size_t)row0 * D_DIM + (k0), sm[b][0]);           \
      STAGE_TILE128(Wqhi + (size_t)n0   * D_DIM + (k0), sm[b][1]);           \
      STAGE_TILE128(Wqlo + (size_t)n0   * D_DIM + (k0), sm[b][2]);           \
    } while (0)
#define STAGE_B(k0, b) do {                                                  \
      STAGE_TILE128(xlo  + (size_t)row0 * D_DIM + (k0), sm[b][0]);           \
      STAGE_TILE128(Wqhi + (size_t)n0   * D_DIM + (k0), sm[b][1]);           \
    } while (0)

    STAGE_A(0, 0);
    __syncthreads();
    int cur = 0;
    // phase A: acc += xh*Wqh + xh*Wql
    for (int k0 = 0; k0 < D_DIM; k0 += 32) {
      if (k0 + 32 < D_DIM) STAGE_A(k0 + 32, cur ^ 1);
      else                 STAGE_B(0, cur ^ 1);       // bridge into phase B
      bf16x8 af[4], bh0[4], bl0[4];
      #pragma unroll
      for (int mi = 0; mi < 4; ++mi)
        af[mi] = FRAG(sm[cur][0], wr * 64 + mi * 16 + lm);
      #pragma unroll
      for (int ni = 0; ni < 4; ++ni) {
        bh0[ni] = FRAG(sm[cur][1], wc * 64 + ni * 16 + lm);
        bl0[ni] = FRAG(sm[cur][2], wc * 64 + ni * 16 + lm);
      }
      #pragma unroll
      for (int mi = 0; mi < 4; ++mi)
        #pragma unroll
        for (int ni = 0; ni < 4; ++ni) {
          acc[mi][ni] = __builtin_amdgcn_mfma_f32_16x16x32_bf16(af[mi], bh0[ni], acc[mi][ni], 0, 0, 0);
          acc[mi][ni] = __builtin_amdgcn_mfma_f32_16x16x32_bf16(af[mi], bl0[ni], acc[mi][ni], 0, 0, 0);
        }
      __syncthreads();
      cur ^= 1;
    }
    // phase B: acc += xl*Wqh
    for (int k0 = 0; k0 < D_DIM; k0 += 32) {
      if (k0 + 32 < D_DIM) STAGE_B(k0 + 32, cur ^ 1);
      bf16x8 af[4], bh0[4];
      #pragma unroll
      for (int mi = 0; mi < 4; ++mi)
        af[mi] = FRAG(sm[cur][0], wr * 64 + mi * 16 + lm);
      #pragma unroll
      for (int ni = 0; ni < 4; ++ni)
        bh0[ni] = FRAG(sm[cur][1], wc * 64 + ni * 16 + lm);
      #pragma unroll
      for (int mi = 0; mi < 4; ++mi)
        #pragma unroll
        for (int ni = 0; ni < 4; ++ni)
          acc[mi][ni] = __builtin_amdgcn_mfma_f32_16x16x32_bf16(af[mi], bh0[ni], acc[mi][ni], 0, 0, 0);
      __syncthreads();
      cur ^= 1;
    }

    float bvv[4];
    #pragma unroll
    for (int ni = 0; ni < 4; ++ni) bvv[ni] = bq[n0 + wc * 64 + ni * 16 + lm];
    #pragma unroll
    for (int mi = 0; mi < 4; ++mi)
      #pragma unroll
      for (int ni = 0; ni < 4; ++ni)
        #pragma unroll
        for (int r = 0; r < 4; ++r) acc[mi][ni][r] += bvv[ni];

    const int h = (n0 + wc * 64) >> 6;
    #pragma unroll
    for (int mi = 0; mi < 4; ++mi)
      #pragma unroll
      for (int r = 0; r < 4; ++r) {
        float s = 0.f;
        #pragma unroll
        for (int ni = 0; ni < 4; ++ni) { float v = acc[mi][ni][r]; s += v * v; }
        s += __shfl_xor(s, 1); s += __shfl_xor(s, 2);
        s += __shfl_xor(s, 4); s += __shfl_xor(s, 8);
        if (lm == 0) {
          int row = row0 + wr * 64 + mi * 16 + quad * 4 + r;
          int bb = row >> 11, ll = row & (L_DIM - 1);
          norms[(bb * H_DIM + h) * L_DIM + ll] = s;
        }
      }

    #pragma unroll
    for (int mi = 0; mi < 4; ++mi)
      #pragma unroll
      for (int r = 0; r < 4; ++r) {
        int row = row0 + wr * 64 + mi * 16 + quad * 4 + r;
        #pragma unroll
        for (int ni = 0; ni < 4; ++ni)
          Qhi[(size_t)row * D_DIM + n0 + wc * 64 + ni * 16 + lm] = (bf16_t)acc[mi][ni][r];
      }
  } else {
    const bf16_t* W = (z == 1) ? Wkb : Wvb;
#define STAGE_L(k0, b) do {                                                  \
      STAGE_TILE128(xhi + (size_t)row0 * D_DIM + (k0), sm[b][0]);            \
      STAGE_TILE128(W   + (size_t)n0   * D_DIM + (k0), sm[b][1]);            \
    } while (0)

    STAGE_L(0, 0);
    __syncthreads();
    int cur = 0;
    for (int k0 = 0; k0 < D_DIM; k0 += 32) {
      if (k0 + 32 < D_DIM) STAGE_L(k0 + 32, cur ^ 1);
      bf16x8 af[4], bfr[4];
      #pragma unroll
      for (int mi = 0; mi < 4; ++mi)
        af[mi] = FRAG(sm[cur][0], wr * 64 + mi * 16 + lm);
      #pragma unroll
      for (int ni = 0; ni < 4; ++ni)
        bfr[ni] = FRAG(sm[cur][1], wc * 64 + ni * 16 + lm);
      #pragma unroll
      for (int mi = 0; mi < 4; ++mi)
        #pragma unroll
        for (int ni = 0; ni < 4; ++ni)
          acc[mi][ni] = __builtin_amdgcn_mfma_f32_16x16x32_bf16(af[mi], bfr[ni], acc[mi][ni], 0, 0, 0);
      __syncthreads();
      cur ^= 1;
    }

    const float* bias = (z == 1) ? bk : bv;
    float bvv[4];
    #pragma unroll
    for (int ni = 0; ni < 4; ++ni) bvv[ni] = bias[n0 + wc * 64 + ni * 16 + lm];
    #pragma unroll
    for (int mi = 0; mi < 4; ++mi)
      #pragma unroll
      for (int ni = 0; ni < 4; ++ni)
        #pragma unroll
        for (int r = 0; r < 4; ++r) acc[mi][ni][r] += bvv[ni];

    const int hh = (n0 + wc * 64) >> 6;   // head 0..15
    if (z == 1) {
      // Khead[b][h][l][64]
      #pragma unroll
      for (int mi = 0; mi < 4; ++mi)
        #pragma unroll
        for (int r = 0; r < 4; ++r) {
          int row = row0 + wr * 64 + mi * 16 + quad * 4 + r;
          int bb = row >> 11, ll = row & (L_DIM - 1);
          size_t base = (size_t)(bb * H_DIM + hh) * HSZ + (size_t)ll * 64;
          #pragma unroll
          for (int ni = 0; ni < 4; ++ni)
            Khi[base + ni * 16 + lm] = (bf16_t)acc[mi][ni][r];
        }
    } else {
      // V key-tiled: [(b,h)][kb=l/32][d][32]
      #pragma unroll
      for (int mi = 0; mi < 4; ++mi) {
        int rbase = row0 + wr * 64 + mi * 16 + quad * 4;
        int bb = rbase >> 11, l0 = rbase & (L_DIM - 1);
        int kbv = l0 >> 5, kin = l0 & 31;
        size_t hb = (size_t)(bb * H_DIM + hh) * HSZ;
        #pragma unroll
        for (int ni = 0; ni < 4; ++ni) {
          int d = ni * 16 + lm;
          bf16x4 wv;
          #pragma unroll
          for (int r = 0; r < 4; ++r) wv[r] = (bf16_t)acc[mi][ni][r];
          *reinterpret_cast<bf16x4*>(&VThi[hb + (size_t)(kbv * 64 + d) * 32 + kin]) = wv;
        }
      }
      // Vmean partial: sum this block's 128 rows per (head, dim), f32.
      const int bb = row0 >> 11;
      float ps[4];
      #pragma unroll
      for (int ni = 0; ni < 4; ++ni) {
        float s = 0.f;
        #pragma unroll
        for (int mi = 0; mi < 4; ++mi)
          #pragma unroll
          for (int r = 0; r < 4; ++r) s += acc[mi][ni][r];
        ps[ni] = s;
      }
      #pragma unroll
      for (int ni = 0; ni < 4; ++ni) {
        ps[ni] += __shfl_xor(ps[ni], 16);
        ps[ni] += __shfl_xor(ps[ni], 32);
      }
      if (quad == 0) {
        #pragma unroll
        for (int ni = 0; ni < 4; ++ni)
          atomicAdd(&Vmeanf[(bb * H_DIM + hh) * 64 + ni * 16 + lm], ps[ni]);
      }
    }
  }
}

// ---------------------------------------------------------------------------
// Output projection: 64x128 tiles, grid (8,64) = 2 blocks/CU, prefetch dbuf.
// ---------------------------------------------------------------------------
__global__ __launch_bounds__(256) void gemm_out(
    const bf16_t* __restrict__ Ahi, const bf16_t* __restrict__ Wob,
    const float* __restrict__ bias, float* __restrict__ C)
{
  const int n0   = blockIdx.x * 128;
  const int row0 = blockIdx.y * 64;

  __shared__ __align__(16) bf16_t sm[2][6144];   // 24 KB: dbuf x (A64 + B128)

  const int tid  = threadIdx.x;
  const int lane = tid & 63;
  const int wave = tid >> 6;
  const int wr = wave >> 1, wc = wave & 1;
  const int lm = lane & 15, quad = lane >> 4;

  const f32x4 vzero = {0.f, 0.f, 0.f, 0.f};
  f32x4 acc[2][4];
  #pragma unroll
  for (int mi = 0; mi < 2; ++mi)
    #pragma unroll
    for (int ni = 0; ni < 4; ++ni) acc[mi][ni] = vzero;

#define STAGE_O(k0, b) do {                                                  \
    STAGE_TILE64(Ahi + (size_t)row0 * D_DIM + (k0), sm[b]);                  \
    STAGE_TILE128(Wob + (size_t)n0 * D_DIM + (k0), sm[b] + 2048);            \
  } while (0)

  STAGE_O(0, 0);
  __syncthreads();
  int cur = 0;
  for (int k0 = 0; k0 < D_DIM; k0 += 32) {
    if (k0 + 32 < D_DIM) STAGE_O(k0 + 32, cur ^ 1);
    bf16x8 af[2], bfr[4];
    #pragma unroll
    for (int mi = 0; mi < 2; ++mi)
      af[mi] = FRAG(sm[cur], wr * 32 + mi * 16 + lm);
    #pragma unroll
    for (int ni = 0; ni < 4; ++ni)
      bfr[ni] = FRAG(sm[cur] + 2048, wc * 64 + ni * 16 + lm);
    #pragma unroll
    for (int mi = 0; mi < 2; ++mi)
      #pragma unroll
      for (int ni = 0; ni < 4; ++ni)
        acc[mi][ni] = __builtin_amdgcn_mfma_f32_16x16x32_bf16(af[mi], bfr[ni], acc[mi][ni], 0, 0, 0);
    __syncthreads();
    cur ^= 1;
  }

  float bvv[4];
  #pragma unroll
  for (int ni = 0; ni < 4; ++ni) bvv[ni] = bias[n0 + wc * 64 + ni * 16 + lm];
  #pragma unroll
  for (int mi = 0; mi < 2; ++mi)
    #pragma unroll
    for (int r = 0; r < 4; ++r) {
      int row = row0 + wr * 32 + mi * 16 + quad * 4 + r;
      #pragma unroll
      for (int ni = 0; ni < 4; ++ni)
        C[(size_t)row * D_DIM + n0 + wc * 64 + ni * 16 + lm] = acc[mi][ni][r] + bvv[ni];
    }
}

// ---------------------------------------------------------------------------
// Exact top-409 per (b,h) via 4-pass 8-bit radix select on f32 bits.
// Wave-parallel suffix scan for bin selection (r11). Writes rowmap for fill.
// ---------------------------------------------------------------------------
__global__ __launch_bounds__(1024) void topk_kernel(
    const float* __restrict__ norms, int* __restrict__ sel,
    int* __restrict__ rowmap)
{
  const int bh = blockIdx.x;
  const int t  = threadIdx.x;
  const int w  = t >> 6;            // wave 0..15
  const int lane = t & 63;

  __shared__ int bins[256];
  __shared__ unsigned int sh_pfx;
  __shared__ int sh_r;
  __shared__ int cnt0[16], cnt1[16], ecnt0[16], ecnt1[16];

  const unsigned int k0 = __float_as_uint(norms[bh * L_DIM + t]);
  const unsigned int k1 = __float_as_uint(norms[bh * L_DIM + t + 1024]);

  // init rowmap (selected rows overwritten at the end)
  rowmap[bh * L_DIM + t] = -1;
  rowmap[bh * L_DIM + t + 1024] = -1;

  unsigned int pfx = 0;
  int r = KTOP;
  #pragma unroll
  for (int p = 0; p < 4; ++p) {
    const int sh = 24 - 8 * p;
    if (t < 256) bins[t] = 0;
    __syncthreads();
    const bool q0 = (p == 0) || ((k0 >> (sh + 8)) == pfx);
    const bool q1 = (p == 0) || ((k1 >> (sh + 8)) == pfx);
    if (q0) atomicAdd(&bins[(k0 >> sh) & 255], 1);
    if (q1) atomicAdd(&bins[(k1 >> sh) & 255], 1);
    __syncthreads();
    if (w == 0) {
      const int b0 = bins[lane * 4 + 0];
      const int b1 = bins[lane * 4 + 1];
      const int b2 = bins[lane * 4 + 2];
      const int b3 = bins[lane * 4 + 3];
      int sfx = b0 + b1 + b2 + b3;
      #pragma unroll
      for (int off = 1; off < 64; off <<= 1) {
        int other = __shfl_down(sfx, off);
        if (lane + off < 64) sfx += other;
      }
      int nsfx = __shfl_down(sfx, 1);
      if (lane == 63) nsfx = 0;
      if (sfx >= r && nsfx < r) {      // unique winner lane
        int cum = nsfx, B, rn;
        if (cum + b3 >= r)      { B = lane * 4 + 3; rn = r - cum; }
        else { cum += b3;
          if (cum + b2 >= r)    { B = lane * 4 + 2; rn = r - cum; }
          else { cum += b2;
            if (cum + b1 >= r)  { B = lane * 4 + 1; rn = r - cum; }
            else { cum += b1;     B = lane * 4 + 0; rn = r - cum; }
          }
        }
        sh_pfx = (pfx << 8) | (unsigned int)B;
        sh_r = rn;
      }
    }
    __syncthreads();
    pfx = sh_pfx;
    r = sh_r;
    __syncthreads();
  }
  const unsigned int T = pfx;

  const bool gt0 = (k0 > T), gt1 = (k1 > T);
  const bool eq0 = (k0 == T), eq1 = (k1 == T);
  const unsigned long long mlt = (lane == 63) ? 0x7fffffffffffffffull
                                              : ((1ull << lane) - 1ull);
  const unsigned long long bg0 = __ballot(gt0);
  const unsigned long long bg1 = __ballot(gt1);
  const unsigned long long be0 = __ballot(eq0);
  const unsigned long long be1 = __ballot(eq1);
  if (lane == 0) {
    cnt0[w]  = __popcll(bg0);
    cnt1[w]  = __popcll(bg1);
    ecnt0[w] = __popcll(be0);
    ecnt1[w] = __popcll(be1);
  }
  __syncthreads();
  int og0 = 0, og1 = 0, oe0 = 0, oe1 = 0;
  int tg0 = 0, tg1 = 0, te0 = 0;
  #pragma unroll
  for (int i = 0; i < 16; ++i) {
    if (i < w) { og0 += cnt0[i]; og1 += cnt1[i]; oe0 += ecnt0[i]; oe1 += ecnt1[i]; }
    tg0 += cnt0[i]; tg1 += cnt1[i]; te0 += ecnt0[i];
  }
  const int G = tg0 + tg1;          // total keys > T (G < KTOP)
  const int take = KTOP - G;        // ties to take, earliest index first
  const int base = bh * SLOTS;

  if (gt0) {
    int slot = og0 + __popcll(bg0 & mlt);
    sel[base + slot] = t;
    rowmap[bh * L_DIM + t] = slot;
  }
  if (gt1) {
    int slot = tg0 + og1 + __popcll(bg1 & mlt);
    sel[base + slot] = t + 1024;
    rowmap[bh * L_DIM + t + 1024] = slot;
  }
  if (eq0) {
    int rk = oe0 + __popcll(be0 & mlt);
    if (rk < take) {
      sel[base + G + rk] = t;
      rowmap[bh * L_DIM + t] = G + rk;
    }
  }
  if (eq1) {
    int rk = te0 + oe1 + __popcll(be1 & mlt);
    if (rk < take) {
      sel[base + G + rk] = t + 1024;
      rowmap[bh * L_DIM + t + 1024] = G + rk;
    }
  }
  if (t < SLOTS - KTOP) sel[base + KTOP + t] = -1;
}

// ---------------------------------------------------------------------------
// K-split flash attention — r12 structure (measured best, 198.8 µs total)
// + setprio(1) around MFMA clusters only (m191: +4-7% attn; the r13 PV
// pipeline is REVERTED — it regressed, likely via register pressure).
// LDS-staged K/V with prefetch dbuf; qt=2; grid 1024 = 4 blocks/CU.
// ---------------------------------------------------------------------------
__global__ __launch_bounds__(256) void attn_kernel(
    const bf16_t* __restrict__ Qhi,
    const bf16_t* __restrict__ Khi,
    const bf16_t* __restrict__ VThi,
    const int* __restrict__ sel,
    float* __restrict__ Ol, bf16_t* __restrict__ Oo)
{
  const int bx = blockIdx.x;
  const int xl = bx & 7;          // XCD id under default round-robin
  const int rest = bx >> 3;       // 0..127
  const int qc = rest & 3;
  const int gh = rest >> 2;       // 0..31
  const int g  = gh * 8 + xl;     // K/V-chunk group 0..255
  const int bh = g & 31;
  const int ks = g >> 5;
  const int b = bh >> 4, h = bh & 15;
  const int wave = threadIdx.x >> 6;
  const int lane = threadIdx.x & 63;
  const int lm = lane & 15, quad = lane >> 4;

  __shared__ __align__(16) bf16_t sK[2][2048];   // 32 keys x 64d, swizzled
  __shared__ __align__(16) bf16_t sV[2][2048];   // 64 d x 32 keys, swizzled
  __shared__ __align__(16) bf16_t sPh[2][2][4][16][40];  // [PB][qt][wave][q][k]

  const int qbase = qc * 128 + wave * 32;   // tile qt covers +qt*16
  bf16x8 qa[2][2];
  #pragma unroll
  for (int qt = 0; qt < 2; ++qt) {
    int qi = sel[bh * SLOTS + qbase + qt * 16 + lm];
    size_t qo = ((size_t)(b * L_DIM + (qi >= 0 ? qi : 0))) * D_DIM + h * 64;
    qa[qt][0] = *reinterpret_cast<const bf16x8*>(&Qhi[qo + quad * 8]);
    qa[qt][1] = *reinterpret_cast<const bf16x8*>(&Qhi[qo + 32 + quad * 8]);
  }

  const f32x4 vzero = {0.f, 0.f, 0.f, 0.f};
  float l_l[2][4];
  f32x4 o[2][4];
  #pragma unroll
  for (int qt = 0; qt < 2; ++qt)
    #pragma unroll
    for (int ni = 0; ni < 4; ++ni) { o[qt][ni] = vzero; l_l[qt][ni] = 0.f; }

  const float scale = 0.125f;
  const size_t khead = (size_t)(b * H_DIM + h) * HSZ;
  const int key0 = ks * KCHUNK;

#define ATTN_STAGE(KT, bsel) do {                                             \
    const int krow = wave * 8 + (lane >> 3);                                  \
    const int kslot = (lane & 7) ^ ((lane >> 3) & 7);                         \
    gld16(&Khi[khead + (size_t)(key0 + (KT) + krow) * 64 + kslot * 8],        \
          sK[bsel] + wave * 512);                                             \
    const int vrow = wave * 16 + (lane >> 2);                                 \
    const int vslot = (lane & 3) ^ ((lane >> 2) & 3);                         \
    const size_t vbase = khead + (size_t)((key0 + (KT)) >> 5) * 2048;         \
    gld16(&VThi[vbase + vrow * 32 + vslot * 8], sV[bsel] + wave * 512);       \
  } while (0)

  ATTN_STAGE(0, 0);
  __syncthreads();
  int cur = 0;
  #pragma unroll 2
  for (int kt = 0; kt < KCHUNK; kt += 32) {
    if (kt + 32 < KCHUNK) ATTN_STAGE(kt + 32, cur ^ 1);
    const int PB = (kt >> 5) & 1;
    const int kx = lm & 7;
    bf16x8 kb0 = *reinterpret_cast<const bf16x8*>(&sK[cur][lm * 64 + ((quad) ^ kx) * 8]);
    bf16x8 kb1 = *reinterpret_cast<const bf16x8*>(&sK[cur][lm * 64 + ((quad + 4) ^ kx) * 8]);
    bf16x8 kb2 = *reinterpret_cast<const bf16x8*>(&sK[cur][(16 + lm) * 64 + ((quad) ^ kx) * 8]);
    bf16x8 kb3 = *reinterpret_cast<const bf16x8*>(&sK[cur][(16 + lm) * 64 + ((quad + 4) ^ kx) * 8]);
    bf16x8 vbh[4];
    #pragma unroll
    for (int ni = 0; ni < 4; ++ni) {
      const int vr = ni * 16 + lm;
      vbh[ni] = *reinterpret_cast<const bf16x8*>(&sV[cur][vr * 32 + ((quad) ^ (vr & 3)) * 8]);
    }
    #pragma unroll
    for (int qt = 0; qt < 2; ++qt) {
      f32x4 s0 = vzero, s1 = vzero;
      __builtin_amdgcn_s_setprio(1);
      s0 = __builtin_amdgcn_mfma_f32_16x16x32_bf16(qa[qt][0], kb0, s0, 0, 0, 0);
      s0 = __builtin_amdgcn_mfma_f32_16x16x32_bf16(qa[qt][1], kb1, s0, 0, 0, 0);
      s1 = __builtin_amdgcn_mfma_f32_16x16x32_bf16(qa[qt][0], kb2, s1, 0, 0, 0);
      s1 = __builtin_amdgcn_mfma_f32_16x16x32_bf16(qa[qt][1], kb3, s1, 0, 0, 0);
      __builtin_amdgcn_s_setprio(0);
      #pragma unroll
      for (int r = 0; r < 4; ++r) {
        float p0 = __expf(s0[r] * scale);
        float p1 = __expf(s1[r] * scale);
        l_l[qt][r] += p0 + p1;
        sPh[PB][qt][wave][quad * 4 + r][lm]      = (bf16_t)p0;
        sPh[PB][qt][wave][quad * 4 + r][16 + lm] = (bf16_t)p1;
      }
      bf16x8 pah = *reinterpret_cast<const bf16x8*>(&sPh[PB][qt][wave][lm][quad * 8]);
      __builtin_amdgcn_s_setprio(1);
      #pragma unroll
      for (int ni = 0; ni < 4; ++ni)
        o[qt][ni] = __builtin_amdgcn_mfma_f32_16x16x32_bf16(pah, vbh[ni], o[qt][ni], 0, 0, 0);
      __builtin_amdgcn_s_setprio(0);
    }
    __syncthreads();
    cur ^= 1;
  }

  #pragma unroll
  for (int qt = 0; qt < 2; ++qt)
    #pragma unroll
    for (int r = 0; r < 4; ++r) {
      l_l[qt][r] += __shfl_xor(l_l[qt][r], 1);
      l_l[qt][r] += __shfl_xor(l_l[qt][r], 2);
      l_l[qt][r] += __shfl_xor(l_l[qt][r], 4);
      l_l[qt][r] += __shfl_xor(l_l[qt][r], 8);
    }

  #pragma unroll
  for (int qt = 0; qt < 2; ++qt)
    #pragma unroll
    for (int r = 0; r < 4; ++r) {
      int slot = qbase + qt * 16 + quad * 4 + r;
      int s2 = sel[bh * SLOTS + slot];
      if (s2 >= 0) {
        size_t gs = (size_t)(bh * SLOTS_IO + slot) * KSPLIT + ks;
        if (lm == 0) Ol[gs] = l_l[qt][r];
        #pragma unroll
        for (int ni = 0; ni < 4; ++ni)
          Oo[gs * 64 + ni * 16 + lm] = (bf16_t)o[qt][ni][r];
      }
    }
}

// ---------------------------------------------------------------------------
// Fused fill: every AO row written exactly once — mean(V) for non-selected,
// ksplit-combine for selected. Grid (32,32) = 4 blocks/CU; per-wave rowmap
// prefetch + shfl broadcast.
// ---------------------------------------------------------------------------
__global__ __launch_bounds__(256) void fill_kernel(
    const float* __restrict__ Ol, const bf16_t* __restrict__ Oo,
    const int* __restrict__ rowmap, const float* __restrict__ Vmeanf,
    bf16_t* __restrict__ AOhi)
{
  const int bh = blockIdx.x;
  const int b = bh >> 4, h = bh & 15;
  const int t = threadIdx.x;
  const int lane = t & 63;
  const int w = t >> 6;

  __shared__ __align__(16) bf16_t smh[64];
  if (t < 64)
    smh[t] = (bf16_t)(Vmeanf[(b * H_DIM + h) * 64 + t] * (1.0f / (float)L_DIM));
  __syncthreads();

  const int rbase = blockIdx.y * 64 + w * 16;   // 16 rows per wave
  int flag = -1;
  if (lane < 16) flag = rowmap[bh * L_DIM + rbase + lane];

  for (int j = 0; j < 16; ++j) {
    const int s = __shfl(flag, j);              // wave-uniform slot or -1
    const int row = rbase + j;
    bf16_t outv;
    if (s < 0) {
      outv = smh[lane];
    } else {
      size_t gs = (size_t)(bh * SLOTS_IO + s) * KSPLIT;
      float L = 0.f, ov = 0.f;
      #pragma unroll
      for (int sp = 0; sp < KSPLIT; ++sp) {
        L  += Ol[gs + sp];
        ov += (float)Oo[(gs + sp) * 64 + lane];
      }
      outv = (bf16_t)(ov / L);
    }
    AOhi[((size_t)(b * L_DIM + row)) * D_DIM + h * 64 + lane] = outv;
  }
}

// ---------------------------------------------------------------------------
extern "C" void kernel_launch(void* const* d_in, const int* in_sizes, int n_in,
                              void* d_out, int out_size, void* d_ws, size_t ws_size,
                              hipStream_t stream) {
  const float* x  = (const float*)d_in[0];
  const float* Wq = (const float*)d_in[1];
  const float* bq = (const float*)d_in[2];
  const float* Wk = (const float*)d_in[3];
  const float* bk = (const float*)d_in[4];
  const float* Wv = (const float*)d_in[5];
  const float* bv = (const float*)d_in[6];
  const float* Wo = (const float*)d_in[7];
  const float* bo = (const float*)d_in[8];
  float* out = (float*)d_out;

  // ws layout (~43 MB):
  //  [0,8)    Qhi  (aliased as AOhi after attn)
  //  [8,16)   VThi (key-tiled per-head layout)
  //  [16,24)  xhi  -+ dead after gemm_qkv; [16,~30.7) reused for Oo (bf16,
  //  [24,32)  xlo  -+  SLOTS_IO=448 stride); [31,32) rowmap (topk, xlo dead)
  //  [32,34)  Wqhi  [34,36) Wqlo  [36,38) Wkb  [38,40) Wvb  [40,42) Wob
  //  [42,..)  norms (256 KB), sel (64 KB), Ol (458 KB), Vmeanf (8 KB @832K)
  // Khi (per-head layout) lives in d_out (8 of 16 MB) — dead until gemm_out.
  const size_t MB = 1u << 20;
  char* ws = (char*)d_ws;
  bf16_t* Qhi  = (bf16_t*)(ws);
  bf16_t* VThi = (bf16_t*)(ws + 8 * MB);
  bf16_t* xhi  = (bf16_t*)(ws + 16 * MB);
  bf16_t* xlo  = (bf16_t*)(ws + 24 * MB);
  bf16_t* Oo   = (bf16_t*)(ws + 16 * MB);         // aliases xhi/xlo
  int*    rowmap = (int*)(ws + 31 * MB);          // 256 KB, past Oo's tail
  bf16_t* Wqhi = (bf16_t*)(ws + 32 * MB);
  bf16_t* Wqlo = (bf16_t*)(ws + 34 * MB);
  bf16_t* Wkb  = (bf16_t*)(ws + 36 * MB);
  bf16_t* Wvb  = (bf16_t*)(ws + 38 * MB);
  bf16_t* Wob  = (bf16_t*)(ws + 40 * MB);
  float*  norms = (float*)(ws + 42 * MB);
  int*    sel   = (int*)(ws + 42 * MB + (256u << 10));
  float*  Ol    = (float*)(ws + 42 * MB + (320u << 10));
  float*  Vmeanf = (float*)(ws + 42 * MB + (832u << 10));
  bf16_t* AOhi = Qhi;
  bf16_t* Khi = (bf16_t*)d_out;

  dim3 blk(256);
  prep_kernel<<<dim3(2048), blk, 0, stream>>>(x, Wq, Wk, Wv, Wo,
                                              xhi, xlo, Wqhi, Wqlo, Wkb, Wvb, Wob,
                                              Vmeanf);
  gemm_qkv<<<dim3(768), blk, 0, stream>>>(xhi, xlo, Wqhi, Wqlo, Wkb, Wvb,
                                          bq, bk, bv, Qhi, Khi, VThi, norms, Vmeanf);
  topk_kernel<<<dim3(32), dim3(1024), 0, stream>>>(norms, sel, rowmap);
  attn_kernel<<<dim3(32 * 4 * KSPLIT), blk, 0, stream>>>(Qhi, Khi, VThi, sel, Ol, Oo);
  fill_kernel<<<dim3(32, 32), blk, 0, stream>>>(Ol, Oo, rowmap, Vmeanf, AOhi);
  gemm_out<<<dim3(8, 64), blk, 0, stream>>>(AOhi, Wob, bo, out);
}

// Round 15
// 202.216 us; speedup vs baseline: 1.0091x; 1.0091x over previous
//
#include <hip/hip_runtime.h>
#include <hip/hip_bf16.h>
#include <math.h>

typedef __bf16 bf16_t;
typedef __bf16 bf16x8 __attribute__((ext_vector_type(8)));
typedef __bf16 bf16x4 __attribute__((ext_vector_type(4)));
typedef float  f32x4  __attribute__((ext_vector_type(4)));

#define L_DIM 2048
#define D_DIM 1024
#define H_DIM 16
#define M_DIM 4096
#define KTOP 409
#define SLOTS 512      // sel padding (128-slot q-chunks; sel = -1 beyond KTOP)
#define SLOTS_IO 448   // Oo/Ol stride (real slots < 448) — keeps 16MB window
#define KSPLIT 8
#define KCHUNK 256     // L_DIM / KSPLIT
#define HSZ (L_DIM * 64)   // elements per (b,h) head block = 131072

// split f32 into bf16 hi + bf16 lo (a ~= hi + lo)
__device__ __forceinline__ void split2(float a, bf16_t& h, bf16_t& l) {
  h = (bf16_t)a;
  l = (bf16_t)(a - (float)h);
}

// async global -> LDS, 16B per lane; lds ptr must be wave-uniform (m104/m108)
__device__ __forceinline__ void gld16(const bf16_t* g, bf16_t* l) {
  __builtin_amdgcn_global_load_lds(
      (const __attribute__((address_space(1))) void*)g,
      (__attribute__((address_space(3))) void*)l, 16, 0, 0);
}

// LDS source-side XOR swizzle (rule #21; perf-neutral measured, kept)
#define STAGE_TILE128(src, dst)                                               \
  {                                                                           \
    const int seg0 = wave * 2;                                                \
    const int r0 = seg0 * 16 + (lane >> 2);                                   \
    const int c0 = (((lane & 3) ^ ((lane >> 2) & 3))) * 8;                    \
    gld16((src) + (size_t)r0 * D_DIM + c0, (dst) + seg0 * 512);               \
    gld16((src) + (size_t)(r0 + 16) * D_DIM + c0, (dst) + (seg0 + 1) * 512);  \
  }

#define STAGE_TILE64(src, dst)                                                \
  {                                                                           \
    const int r0 = wave * 16 + (lane >> 2);                                   \
    const int c0 = (((lane & 3) ^ ((lane >> 2) & 3))) * 8;                    \
    gld16((src) + (size_t)r0 * D_DIM + c0, (dst) + wave * 512);               \
  }

#define FRAG(buf, ROW) \
  (*reinterpret_cast<const bf16x8*>(&(buf)[(ROW) * 32 + (quad ^ (lm & 3)) * 8]))

// ---------------------------------------------------------------------------
// prep: pre-split x and Wq into bf16 hi/lo; pre-round Wk/Wv/Wo to bf16.
// Also zeroes the Vmean accumulator (2048 f32 = 512 f32x4 items).
// ---------------------------------------------------------------------------
__global__ __launch_bounds__(256) void prep_kernel(
    const float* __restrict__ x,  const float* __restrict__ Wq,
    const float* __restrict__ Wk, const float* __restrict__ Wv,
    const float* __restrict__ Wo,
    bf16_t* __restrict__ xhi, bf16_t* __restrict__ xlo,
    bf16_t* __restrict__ Wqhi, bf16_t* __restrict__ Wqlo,
    bf16_t* __restrict__ Wkb,  bf16_t* __restrict__ Wvb,
    bf16_t* __restrict__ Wob,  float* __restrict__ Vmeanf)
{
  const int XV = (M_DIM * D_DIM) / 4;
  const int WV = (D_DIM * D_DIM) / 4;
  const int TOT = XV + 4 * WV + 512;
  for (int i = blockIdx.x * 256 + threadIdx.x; i < TOT; i += gridDim.x * 256) {
    if (i < XV) {
      f32x4 v = ((const f32x4*)x)[i];
      bf16x4 h, l;
      #pragma unroll
      for (int j = 0; j < 4; ++j) { bf16_t hh, ll; split2(v[j], hh, ll); h[j] = hh; l[j] = ll; }
      ((bf16x4*)xhi)[i] = h;
      ((bf16x4*)xlo)[i] = l;
    } else if (i < XV + WV) {
      int j0 = i - XV;
      f32x4 v = ((const f32x4*)Wq)[j0];
      bf16x4 h, l;
      #pragma unroll
      for (int j = 0; j < 4; ++j) { bf16_t hh, ll; split2(v[j], hh, ll); h[j] = hh; l[j] = ll; }
      ((bf16x4*)Wqhi)[j0] = h;
      ((bf16x4*)Wqlo)[j0] = l;
    } else if (i < XV + 2 * WV) {
      int j0 = i - XV - WV;
      f32x4 v = ((const f32x4*)Wk)[j0];
      bf16x4 h;
      #pragma unroll
      for (int j = 0; j < 4; ++j) h[j] = (bf16_t)v[j];
      ((bf16x4*)Wkb)[j0] = h;
    } else if (i < XV + 3 * WV) {
      int j0 = i - XV - 2 * WV;
      f32x4 v = ((const f32x4*)Wv)[j0];
      bf16x4 h;
      #pragma unroll
      for (int j = 0; j < 4; ++j) h[j] = (bf16_t)v[j];
      ((bf16x4*)Wvb)[j0] = h;
    } else if (i < XV + 4 * WV) {
      int j0 = i - XV - 3 * WV;
      f32x4 v = ((const f32x4*)Wo)[j0];
      bf16x4 h;
      #pragma unroll
      for (int j = 0; j < 4; ++j) h[j] = (bf16_t)v[j];
      ((bf16x4*)Wob)[j0] = h;
    } else {
      int j0 = i - XV - 4 * WV;           // 0..511
      f32x4 zz = {0.f, 0.f, 0.f, 0.f};
      ((f32x4*)Vmeanf)[j0] = zz;
    }
  }
}

// ---------------------------------------------------------------------------
// Fused QKV projections — r5 structure (measured best, 3 blocks/CU).
// z0 split into A/B phases at 48 KB LDS, prefetch dbuf.
// K written per-head [b][h][L][64]; V key-tiled [(b,h)][kb][d][32].
// z2 epilogue accumulates column-sums of V into Vmeanf (f32 atomics).
// ---------------------------------------------------------------------------
__global__ __launch_bounds__(256, 3) void gemm_qkv(
    const bf16_t* __restrict__ xhi, const bf16_t* __restrict__ xlo,
    const bf16_t* __restrict__ Wqhi, const bf16_t* __restrict__ Wqlo,
    const bf16_t* __restrict__ Wkb, const bf16_t* __restrict__ Wvb,
    const float* __restrict__ bq, const float* __restrict__ bk, const float* __restrict__ bv,
    bf16_t* __restrict__ Qhi, bf16_t* __restrict__ Khi, bf16_t* __restrict__ VThi,
    float* __restrict__ norms, float* __restrict__ Vmeanf)
{
  const int bx = blockIdx.x;
  const int z  = bx % 3;          // interleaved so each CU gets a z-mix
  const int id = bx / 3;          // 0..255
  const int n0   = (id & 7) * 128;
  const int row0 = (id >> 3) * 128;

  __shared__ __align__(16) bf16_t sm[2][3][4096];   // 48 KB: dbuf x 3 tiles

  const int tid  = threadIdx.x;
  const int lane = tid & 63;
  const int wave = tid >> 6;
  const int wr = wave >> 1, wc = wave & 1;
  const int lm = lane & 15, quad = lane >> 4;

  const f32x4 vzero = {0.f, 0.f, 0.f, 0.f};
  f32x4 acc[4][4];
  #pragma unroll
  for (int mi = 0; mi < 4; ++mi)
    #pragma unroll
    for (int ni = 0; ni < 4; ++ni) acc[mi][ni] = vzero;

  if (z == 0) {
#define STAGE_A(k0, b) do {                                                  \
      STAGE_TILE128(xhi  + (size_t)row0 * D_DIM + (k0), sm[b][0]);           \
      STAGE_TILE128(Wqhi + (size_t)n0   * D_DIM + (k0), sm[b][1]);           \
      STAGE_TILE128(Wqlo + (size_t)n0   * D_DIM + (k0), sm[b][2]);           \
    } while (0)
#define STAGE_B(k0, b) do {                                                  \
      STAGE_TILE128(xlo  + (size_t)row0 * D_DIM + (k0), sm[b][0]);           \
      STAGE_TILE128(Wqhi + (size_t)n0   * D_DIM + (k0), sm[b][1]);           \
    } while (0)

    STAGE_A(0, 0);
    __syncthreads();
    int cur = 0;
    // phase A: acc += xh*Wqh + xh*Wql
    for (int k0 = 0; k0 < D_DIM; k0 += 32) {
      if (k0 + 32 < D_DIM) STAGE_A(k0 + 32, cur ^ 1);
      else                 STAGE_B(0, cur ^ 1);       // bridge into phase B
      bf16x8 af[4], bh0[4], bl0[4];
      #pragma unroll
      for (int mi = 0; mi < 4; ++mi)
        af[mi] = FRAG(sm[cur][0], wr * 64 + mi * 16 + lm);
      #pragma unroll
      for (int ni = 0; ni < 4; ++ni) {
        bh0[ni] = FRAG(sm[cur][1], wc * 64 + ni * 16 + lm);
        bl0[ni] = FRAG(sm[cur][2], wc * 64 + ni * 16 + lm);
      }
      #pragma unroll
      for (int mi = 0; mi < 4; ++mi)
        #pragma unroll
        for (int ni = 0; ni < 4; ++ni) {
          acc[mi][ni] = __builtin_amdgcn_mfma_f32_16x16x32_bf16(af[mi], bh0[ni], acc[mi][ni], 0, 0, 0);
          acc[mi][ni] = __builtin_amdgcn_mfma_f32_16x16x32_bf16(af[mi], bl0[ni], acc[mi][ni], 0, 0, 0);
        }
      __syncthreads();
      cur ^= 1;
    }
    // phase B: acc += xl*Wqh
    for (int k0 = 0; k0 < D_DIM; k0 += 32) {
      if (k0 + 32 < D_DIM) STAGE_B(k0 + 32, cur ^ 1);
      bf16x8 af[4], bh0[4];
      #pragma unroll
      for (int mi = 0; mi < 4; ++mi)
        af[mi] = FRAG(sm[cur][0], wr * 64 + mi * 16 + lm);
      #pragma unroll
      for (int ni = 0; ni < 4; ++ni)
        bh0[ni] = FRAG(sm[cur][1], wc * 64 + ni * 16 + lm);
      #pragma unroll
      for (int mi = 0; mi < 4; ++mi)
        #pragma unroll
        for (int ni = 0; ni < 4; ++ni)
          acc[mi][ni] = __builtin_amdgcn_mfma_f32_16x16x32_bf16(af[mi], bh0[ni], acc[mi][ni], 0, 0, 0);
      __syncthreads();
      cur ^= 1;
    }

    float bvv[4];
    #pragma unroll
    for (int ni = 0; ni < 4; ++ni) bvv[ni] = bq[n0 + wc * 64 + ni * 16 + lm];
    #pragma unroll
    for (int mi = 0; mi < 4; ++mi)
      #pragma unroll
      for (int ni = 0; ni < 4; ++ni)
        #pragma unroll
        for (int r = 0; r < 4; ++r) acc[mi][ni][r] += bvv[ni];

    const int h = (n0 + wc * 64) >> 6;
    #pragma unroll
    for (int mi = 0; mi < 4; ++mi)
      #pragma unroll
      for (int r = 0; r < 4; ++r) {
        float s = 0.f;
        #pragma unroll
        for (int ni = 0; ni < 4; ++ni) { float v = acc[mi][ni][r]; s += v * v; }
        s += __shfl_xor(s, 1); s += __shfl_xor(s, 2);
        s += __shfl_xor(s, 4); s += __shfl_xor(s, 8);
        if (lm == 0) {
          int row = row0 + wr * 64 + mi * 16 + quad * 4 + r;
          int bb = row >> 11, ll = row & (L_DIM - 1);
          norms[(bb * H_DIM + h) * L_DIM + ll] = s;
        }
      }

    #pragma unroll
    for (int mi = 0; mi < 4; ++mi)
      #pragma unroll
      for (int r = 0; r < 4; ++r) {
        int row = row0 + wr * 64 + mi * 16 + quad * 4 + r;
        #pragma unroll
        for (int ni = 0; ni < 4; ++ni)
          Qhi[(size_t)row * D_DIM + n0 + wc * 64 + ni * 16 + lm] = (bf16_t)acc[mi][ni][r];
      }
  } else {
    const bf16_t* W = (z == 1) ? Wkb : Wvb;
#define STAGE_L(k0, b) do {                                                  \
      STAGE_TILE128(xhi + (size_t)row0 * D_DIM + (k0), sm[b][0]);            \
      STAGE_TILE128(W   + (size_t)n0   * D_DIM + (k0), sm[b][1]);            \
    } while (0)

    STAGE_L(0, 0);
    __syncthreads();
    int cur = 0;
    for (int k0 = 0; k0 < D_DIM; k0 += 32) {
      if (k0 + 32 < D_DIM) STAGE_L(k0 + 32, cur ^ 1);
      bf16x8 af[4], bfr[4];
      #pragma unroll
      for (int mi = 0; mi < 4; ++mi)
        af[mi] = FRAG(sm[cur][0], wr * 64 + mi * 16 + lm);
      #pragma unroll
      for (int ni = 0; ni < 4; ++ni)
        bfr[ni] = FRAG(sm[cur][1], wc * 64 + ni * 16 + lm);
      #pragma unroll
      for (int mi = 0; mi < 4; ++mi)
        #pragma unroll
        for (int ni = 0; ni < 4; ++ni)
          acc[mi][ni] = __builtin_amdgcn_mfma_f32_16x16x32_bf16(af[mi], bfr[ni], acc[mi][ni], 0, 0, 0);
      __syncthreads();
      cur ^= 1;
    }

    const float* bias = (z == 1) ? bk : bv;
    float bvv[4];
    #pragma unroll
    for (int ni = 0; ni < 4; ++ni) bvv[ni] = bias[n0 + wc * 64 + ni * 16 + lm];
    #pragma unroll
    for (int mi = 0; mi < 4; ++mi)
      #pragma unroll
      for (int ni = 0; ni < 4; ++ni)
        #pragma unroll
        for (int r = 0; r < 4; ++r) acc[mi][ni][r] += bvv[ni];

    const int hh = (n0 + wc * 64) >> 6;   // head 0..15
    if (z == 1) {
      // Khead[b][h][l][64]
      #pragma unroll
      for (int mi = 0; mi < 4; ++mi)
        #pragma unroll
        for (int r = 0; r < 4; ++r) {
          int row = row0 + wr * 64 + mi * 16 + quad * 4 + r;
          int bb = row >> 11, ll = row & (L_DIM - 1);
          size_t base = (size_t)(bb * H_DIM + hh) * HSZ + (size_t)ll * 64;
          #pragma unroll
          for (int ni = 0; ni < 4; ++ni)
            Khi[base + ni * 16 + lm] = (bf16_t)acc[mi][ni][r];
        }
    } else {
      // V key-tiled: [(b,h)][kb=l/32][d][32]
      #pragma unroll
      for (int mi = 0; mi < 4; ++mi) {
        int rbase = row0 + wr * 64 + mi * 16 + quad * 4;
        int bb = rbase >> 11, l0 = rbase & (L_DIM - 1);
        int kbv = l0 >> 5, kin = l0 & 31;
        size_t hb = (size_t)(bb * H_DIM + hh) * HSZ;
        #pragma unroll
        for (int ni = 0; ni < 4; ++ni) {
          int d = ni * 16 + lm;
          bf16x4 wv;
          #pragma unroll
          for (int r = 0; r < 4; ++r) wv[r] = (bf16_t)acc[mi][ni][r];
          *reinterpret_cast<bf16x4*>(&VThi[hb + (size_t)(kbv * 64 + d) * 32 + kin]) = wv;
        }
      }
      // Vmean partial: sum this block's 128 rows per (head, dim), f32.
      const int bb = row0 >> 11;
      float ps[4];
      #pragma unroll
      for (int ni = 0; ni < 4; ++ni) {
        float s = 0.f;
        #pragma unroll
        for (int mi = 0; mi < 4; ++mi)
          #pragma unroll
          for (int r = 0; r < 4; ++r) s += acc[mi][ni][r];
        ps[ni] = s;
      }
      #pragma unroll
      for (int ni = 0; ni < 4; ++ni) {
        ps[ni] += __shfl_xor(ps[ni], 16);
        ps[ni] += __shfl_xor(ps[ni], 32);
      }
      if (quad == 0) {
        #pragma unroll
        for (int ni = 0; ni < 4; ++ni)
          atomicAdd(&Vmeanf[(bb * H_DIM + hh) * 64 + ni * 16 + lm], ps[ni]);
      }
    }
  }
}

// ---------------------------------------------------------------------------
// Output projection: 64x128 tiles, grid (8,64) = 2 blocks/CU, prefetch dbuf.
// ---------------------------------------------------------------------------
__global__ __launch_bounds__(256) void gemm_out(
    const bf16_t* __restrict__ Ahi, const bf16_t* __restrict__ Wob,
    const float* __restrict__ bias, float* __restrict__ C)
{
  const int n0   = blockIdx.x * 128;
  const int row0 = blockIdx.y * 64;

  __shared__ __align__(16) bf16_t sm[2][6144];   // 24 KB: dbuf x (A64 + B128)

  const int tid  = threadIdx.x;
  const int lane = tid & 63;
  const int wave = tid >> 6;
  const int wr = wave >> 1, wc = wave & 1;
  const int lm = lane & 15, quad = lane >> 4;

  const f32x4 vzero = {0.f, 0.f, 0.f, 0.f};
  f32x4 acc[2][4];
  #pragma unroll
  for (int mi = 0; mi < 2; ++mi)
    #pragma unroll
    for (int ni = 0; ni < 4; ++ni) acc[mi][ni] = vzero;

#define STAGE_O(k0, b) do {                                                  \
    STAGE_TILE64(Ahi + (size_t)row0 * D_DIM + (k0), sm[b]);                  \
    STAGE_TILE128(Wob + (size_t)n0 * D_DIM + (k0), sm[b] + 2048);            \
  } while (0)

  STAGE_O(0, 0);
  __syncthreads();
  int cur = 0;
  for (int k0 = 0; k0 < D_DIM; k0 += 32) {
    if (k0 + 32 < D_DIM) STAGE_O(k0 + 32, cur ^ 1);
    bf16x8 af[2], bfr[4];
    #pragma unroll
    for (int mi = 0; mi < 2; ++mi)
      af[mi] = FRAG(sm[cur], wr * 32 + mi * 16 + lm);
    #pragma unroll
    for (int ni = 0; ni < 4; ++ni)
      bfr[ni] = FRAG(sm[cur] + 2048, wc * 64 + ni * 16 + lm);
    #pragma unroll
    for (int mi = 0; mi < 2; ++mi)
      #pragma unroll
      for (int ni = 0; ni < 4; ++ni)
        acc[mi][ni] = __builtin_amdgcn_mfma_f32_16x16x32_bf16(af[mi], bfr[ni], acc[mi][ni], 0, 0, 0);
    __syncthreads();
    cur ^= 1;
  }

  float bvv[4];
  #pragma unroll
  for (int ni = 0; ni < 4; ++ni) bvv[ni] = bias[n0 + wc * 64 + ni * 16 + lm];
  #pragma unroll
  for (int mi = 0; mi < 2; ++mi)
    #pragma unroll
    for (int r = 0; r < 4; ++r) {
      int row = row0 + wr * 32 + mi * 16 + quad * 4 + r;
      #pragma unroll
      for (int ni = 0; ni < 4; ++ni)
        C[(size_t)row * D_DIM + n0 + wc * 64 + ni * 16 + lm] = acc[mi][ni][r] + bvv[ni];
    }
}

// ---------------------------------------------------------------------------
// Exact top-409 per (b,h) via 4-pass 8-bit radix select on f32 bits.
// Wave-parallel suffix scan for bin selection (r11). Writes rowmap for fill.
// ---------------------------------------------------------------------------
__global__ __launch_bounds__(1024) void topk_kernel(
    const float* __restrict__ norms, int* __restrict__ sel,
    int* __restrict__ rowmap)
{
  const int bh = blockIdx.x;
  const int t  = threadIdx.x;
  const int w  = t >> 6;            // wave 0..15
  const int lane = t & 63;

  __shared__ int bins[256];
  __shared__ unsigned int sh_pfx;
  __shared__ int sh_r;
  __shared__ int cnt0[16], cnt1[16], ecnt0[16], ecnt1[16];

  const unsigned int k0 = __float_as_uint(norms[bh * L_DIM + t]);
  const unsigned int k1 = __float_as_uint(norms[bh * L_DIM + t + 1024]);

  // init rowmap (selected rows overwritten at the end)
  rowmap[bh * L_DIM + t] = -1;
  rowmap[bh * L_DIM + t + 1024] = -1;

  unsigned int pfx = 0;
  int r = KTOP;
  #pragma unroll
  for (int p = 0; p < 4; ++p) {
    const int sh = 24 - 8 * p;
    if (t < 256) bins[t] = 0;
    __syncthreads();
    const bool q0 = (p == 0) || ((k0 >> (sh + 8)) == pfx);
    const bool q1 = (p == 0) || ((k1 >> (sh + 8)) == pfx);
    if (q0) atomicAdd(&bins[(k0 >> sh) & 255], 1);
    if (q1) atomicAdd(&bins[(k1 >> sh) & 255], 1);
    __syncthreads();
    if (w == 0) {
      const int b0 = bins[lane * 4 + 0];
      const int b1 = bins[lane * 4 + 1];
      const int b2 = bins[lane * 4 + 2];
      const int b3 = bins[lane * 4 + 3];
      int sfx = b0 + b1 + b2 + b3;
      #pragma unroll
      for (int off = 1; off < 64; off <<= 1) {
        int other = __shfl_down(sfx, off);
        if (lane + off < 64) sfx += other;
      }
      int nsfx = __shfl_down(sfx, 1);
      if (lane == 63) nsfx = 0;
      if (sfx >= r && nsfx < r) {      // unique winner lane
        int cum = nsfx, B, rn;
        if (cum + b3 >= r)      { B = lane * 4 + 3; rn = r - cum; }
        else { cum += b3;
          if (cum + b2 >= r)    { B = lane * 4 + 2; rn = r - cum; }
          else { cum += b2;
            if (cum + b1 >= r)  { B = lane * 4 + 1; rn = r - cum; }
            else { cum += b1;     B = lane * 4 + 0; rn = r - cum; }
          }
        }
        sh_pfx = (pfx << 8) | (unsigned int)B;
        sh_r = rn;
      }
    }
    __syncthreads();
    pfx = sh_pfx;
    r = sh_r;
    __syncthreads();
  }
  const unsigned int T = pfx;

  const bool gt0 = (k0 > T), gt1 = (k1 > T);
  const bool eq0 = (k0 == T), eq1 = (k1 == T);
  const unsigned long long mlt = (lane == 63) ? 0x7fffffffffffffffull
                                              : ((1ull << lane) - 1ull);
  const unsigned long long bg0 = __ballot(gt0);
  const unsigned long long bg1 = __ballot(gt1);
  const unsigned long long be0 = __ballot(eq0);
  const unsigned long long be1 = __ballot(eq1);
  if (lane == 0) {
    cnt0[w]  = __popcll(bg0);
    cnt1[w]  = __popcll(bg1);
    ecnt0[w] = __popcll(be0);
    ecnt1[w] = __popcll(be1);
  }
  __syncthreads();
  int og0 = 0, og1 = 0, oe0 = 0, oe1 = 0;
  int tg0 = 0, tg1 = 0, te0 = 0;
  #pragma unroll
  for (int i = 0; i < 16; ++i) {
    if (i < w) { og0 += cnt0[i]; og1 += cnt1[i]; oe0 += ecnt0[i]; oe1 += ecnt1[i]; }
    tg0 += cnt0[i]; tg1 += cnt1[i]; te0 += ecnt0[i];
  }
  const int G = tg0 + tg1;          // total keys > T (G < KTOP)
  const int take = KTOP - G;        // ties to take, earliest index first
  const int base = bh * SLOTS;

  if (gt0) {
    int slot = og0 + __popcll(bg0 & mlt);
    sel[base + slot] = t;
    rowmap[bh * L_DIM + t] = slot;
  }
  if (gt1) {
    int slot = tg0 + og1 + __popcll(bg1 & mlt);
    sel[base + slot] = t + 1024;
    rowmap[bh * L_DIM + t + 1024] = slot;
  }
  if (eq0) {
    int rk = oe0 + __popcll(be0 & mlt);
    if (rk < take) {
      sel[base + G + rk] = t;
      rowmap[bh * L_DIM + t] = G + rk;
    }
  }
  if (eq1) {
    int rk = te0 + oe1 + __popcll(be1 & mlt);
    if (rk < take) {
      sel[base + G + rk] = t + 1024;
      rowmap[bh * L_DIM + t + 1024] = G + rk;
    }
  }
  if (t < SLOTS - KTOP) sel[base + KTOP + t] = -1;
}

// ---------------------------------------------------------------------------
// K-split flash attention — r12 structure exactly (measured best, 198.8 µs
// total). setprio STRIPPED (r14 A/B: +5 µs on this barrier-synced lockstep
// structure, consistent with m190's GEMM null — T5 needs wave role
// diversity, which a 4-wave barrier-synced loop lacks).
// LDS-staged K/V with prefetch dbuf; qt=2; grid 1024 = 4 blocks/CU.
// ---------------------------------------------------------------------------
__global__ __launch_bounds__(256) void attn_kernel(
    const bf16_t* __restrict__ Qhi,
    const bf16_t* __restrict__ Khi,
    const bf16_t* __restrict__ VThi,
    const int* __restrict__ sel,
    float* __restrict__ Ol, bf16_t* __restrict__ Oo)
{
  const int bx = blockIdx.x;
  const int xl = bx & 7;          // XCD id under default round-robin
  const int rest = bx >> 3;       // 0..127
  const int qc = rest & 3;
  const int gh = rest >> 2;       // 0..31
  const int g  = gh * 8 + xl;     // K/V-chunk group 0..255
  const int bh = g & 31;
  const int ks = g >> 5;
  const int b = bh >> 4, h = bh & 15;
  const int wave = threadIdx.x >> 6;
  const int lane = threadIdx.x & 63;
  const int lm = lane & 15, quad = lane >> 4;

  __shared__ __align__(16) bf16_t sK[2][2048];   // 32 keys x 64d, swizzled
  __shared__ __align__(16) bf16_t sV[2][2048];   // 64 d x 32 keys, swizzled
  __shared__ __align__(16) bf16_t sPh[2][2][4][16][40];  // [PB][qt][wave][q][k]

  const int qbase = qc * 128 + wave * 32;   // tile qt covers +qt*16
  bf16x8 qa[2][2];
  #pragma unroll
  for (int qt = 0; qt < 2; ++qt) {
    int qi = sel[bh * SLOTS + qbase + qt * 16 + lm];
    size_t qo = ((size_t)(b * L_DIM + (qi >= 0 ? qi : 0))) * D_DIM + h * 64;
    qa[qt][0] = *reinterpret_cast<const bf16x8*>(&Qhi[qo + quad * 8]);
    qa[qt][1] = *reinterpret_cast<const bf16x8*>(&Qhi[qo + 32 + quad * 8]);
  }

  const f32x4 vzero = {0.f, 0.f, 0.f, 0.f};
  float l_l[2][4];
  f32x4 o[2][4];
  #pragma unroll
  for (int qt = 0; qt < 2; ++qt)
    #pragma unroll
    for (int ni = 0; ni < 4; ++ni) { o[qt][ni] = vzero; l_l[qt][ni] = 0.f; }

  const float scale = 0.125f;
  const size_t khead = (size_t)(b * H_DIM + h) * HSZ;
  const int key0 = ks * KCHUNK;

#define ATTN_STAGE(KT, bsel) do {                                             \
    const int krow = wave * 8 + (lane >> 3);                                  \
    const int kslot = (lane & 7) ^ ((lane >> 3) & 7);                         \
    gld16(&Khi[khead + (size_t)(key0 + (KT) + krow) * 64 + kslot * 8],        \
          sK[bsel] + wave * 512);                                             \
    const int vrow = wave * 16 + (lane >> 2);                                 \
    const int vslot = (lane & 3) ^ ((lane >> 2) & 3);                         \
    const size_t vbase = khead + (size_t)((key0 + (KT)) >> 5) * 2048;         \
    gld16(&VThi[vbase + vrow * 32 + vslot * 8], sV[bsel] + wave * 512);       \
  } while (0)

  ATTN_STAGE(0, 0);
  __syncthreads();
  int cur = 0;
  #pragma unroll 2
  for (int kt = 0; kt < KCHUNK; kt += 32) {
    if (kt + 32 < KCHUNK) ATTN_STAGE(kt + 32, cur ^ 1);
    const int PB = (kt >> 5) & 1;
    const int kx = lm & 7;
    bf16x8 kb0 = *reinterpret_cast<const bf16x8*>(&sK[cur][lm * 64 + ((quad) ^ kx) * 8]);
    bf16x8 kb1 = *reinterpret_cast<const bf16x8*>(&sK[cur][lm * 64 + ((quad + 4) ^ kx) * 8]);
    bf16x8 kb2 = *reinterpret_cast<const bf16x8*>(&sK[cur][(16 + lm) * 64 + ((quad) ^ kx) * 8]);
    bf16x8 kb3 = *reinterpret_cast<const bf16x8*>(&sK[cur][(16 + lm) * 64 + ((quad + 4) ^ kx) * 8]);
    bf16x8 vbh[4];
    #pragma unroll
    for (int ni = 0; ni < 4; ++ni) {
      const int vr = ni * 16 + lm;
      vbh[ni] = *reinterpret_cast<const bf16x8*>(&sV[cur][vr * 32 + ((quad) ^ (vr & 3)) * 8]);
    }
    #pragma unroll
    for (int qt = 0; qt < 2; ++qt) {
      f32x4 s0 = vzero, s1 = vzero;
      s0 = __builtin_amdgcn_mfma_f32_16x16x32_bf16(qa[qt][0], kb0, s0, 0, 0, 0);
      s0 = __builtin_amdgcn_mfma_f32_16x16x32_bf16(qa[qt][1], kb1, s0, 0, 0, 0);
      s1 = __builtin_amdgcn_mfma_f32_16x16x32_bf16(qa[qt][0], kb2, s1, 0, 0, 0);
      s1 = __builtin_amdgcn_mfma_f32_16x16x32_bf16(qa[qt][1], kb3, s1, 0, 0, 0);
      #pragma unroll
      for (int r = 0; r < 4; ++r) {
        float p0 = __expf(s0[r] * scale);
        float p1 = __expf(s1[r] * scale);
        l_l[qt][r] += p0 + p1;
        sPh[PB][qt][wave][quad * 4 + r][lm]      = (bf16_t)p0;
        sPh[PB][qt][wave][quad * 4 + r][16 + lm] = (bf16_t)p1;
      }
      bf16x8 pah = *reinterpret_cast<const bf16x8*>(&sPh[PB][qt][wave][lm][quad * 8]);
      #pragma unroll
      for (int ni = 0; ni < 4; ++ni)
        o[qt][ni] = __builtin_amdgcn_mfma_f32_16x16x32_bf16(pah, vbh[ni], o[qt][ni], 0, 0, 0);
    }
    __syncthreads();
    cur ^= 1;
  }

  #pragma unroll
  for (int qt = 0; qt < 2; ++qt)
    #pragma unroll
    for (int r = 0; r < 4; ++r) {
      l_l[qt][r] += __shfl_xor(l_l[qt][r], 1);
      l_l[qt][r] += __shfl_xor(l_l[qt][r], 2);
      l_l[qt][r] += __shfl_xor(l_l[qt][r], 4);
      l_l[qt][r] += __shfl_xor(l_l[qt][r], 8);
    }

  #pragma unroll
  for (int qt = 0; qt < 2; ++qt)
    #pragma unroll
    for (int r = 0; r < 4; ++r) {
      int slot = qbase + qt * 16 + quad * 4 + r;
      int s2 = sel[bh * SLOTS + slot];
      if (s2 >= 0) {
        size_t gs = (size_t)(bh * SLOTS_IO + slot) * KSPLIT + ks;
        if (lm == 0) Ol[gs] = l_l[qt][r];
        #pragma unroll
        for (int ni = 0; ni < 4; ++ni)
          Oo[gs * 64 + ni * 16 + lm] = (bf16_t)o[qt][ni][r];
      }
    }
}

// ---------------------------------------------------------------------------
// Fused fill: every AO row written exactly once — mean(V) for non-selected,
// ksplit-combine for selected. Grid (32,32) = 4 blocks/CU; per-wave rowmap
// prefetch + shfl broadcast.
// ---------------------------------------------------------------------------
__global__ __launch_bounds__(256) void fill_kernel(
    const float* __restrict__ Ol, const bf16_t* __restrict__ Oo,
    const int* __restrict__ rowmap, const float* __restrict__ Vmeanf,
    bf16_t* __restrict__ AOhi)
{
  const int bh = blockIdx.x;
  const int b = bh >> 4, h = bh & 15;
  const int t = threadIdx.x;
  const int lane = t & 63;
  const int w = t >> 6;

  __shared__ __align__(16) bf16_t smh[64];
  if (t < 64)
    smh[t] = (bf16_t)(Vmeanf[(b * H_DIM + h) * 64 + t] * (1.0f / (float)L_DIM));
  __syncthreads();

  const int rbase = blockIdx.y * 64 + w * 16;   // 16 rows per wave
  int flag = -1;
  if (lane < 16) flag = rowmap[bh * L_DIM + rbase + lane];

  for (int j = 0; j < 16; ++j) {
    const int s = __shfl(flag, j);              // wave-uniform slot or -1
    const int row = rbase + j;
    bf16_t outv;
    if (s < 0) {
      outv = smh[lane];
    } else {
      size_t gs = (size_t)(bh * SLOTS_IO + s) * KSPLIT;
      float L = 0.f, ov = 0.f;
      #pragma unroll
      for (int sp = 0; sp < KSPLIT; ++sp) {
        L  += Ol[gs + sp];
        ov += (float)Oo[(gs + sp) * 64 + lane];
      }
      outv = (bf16_t)(ov / L);
    }
    AOhi[((size_t)(b * L_DIM + row)) * D_DIM + h * 64 + lane] = outv;
  }
}

// ---------------------------------------------------------------------------
extern "C" void kernel_launch(void* const* d_in, const int* in_sizes, int n_in,
                              void* d_out, int out_size, void* d_ws, size_t ws_size,
                              hipStream_t stream) {
  const float* x  = (const float*)d_in[0];
  const float* Wq = (const float*)d_in[1];
  const float* bq = (const float*)d_in[2];
  const float* Wk = (const float*)d_in[3];
  const float* bk = (const float*)d_in[4];
  const float* Wv = (const float*)d_in[5];
  const float* bv = (const float*)d_in[6];
  const float* Wo = (const float*)d_in[7];
  const float* bo = (const float*)d_in[8];
  float* out = (float*)d_out;

  // ws layout (~43 MB):
  //  [0,8)    Qhi  (aliased as AOhi after attn)
  //  [8,16)   VThi (key-tiled per-head layout)
  //  [16,24)  xhi  -+ dead after gemm_qkv; [16,~30.7) reused for Oo (bf16,
  //  [24,32)  xlo  -+  SLOTS_IO=448 stride); [31,32) rowmap (topk, xlo dead)
  //  [32,34)  Wqhi  [34,36) Wqlo  [36,38) Wkb  [38,40) Wvb  [40,42) Wob
  //  [42,..)  norms (256 KB), sel (64 KB), Ol (458 KB), Vmeanf (8 KB @832K)
  // Khi (per-head layout) lives in d_out (8 of 16 MB) — dead until gemm_out.
  const size_t MB = 1u << 20;
  char* ws = (char*)d_ws;
  bf16_t* Qhi  = (bf16_t*)(ws);
  bf16_t* VThi = (bf16_t*)(ws + 8 * MB);
  bf16_t* xhi  = (bf16_t*)(ws + 16 * MB);
  bf16_t* xlo  = (bf16_t*)(ws + 24 * MB);
  bf16_t* Oo   = (bf16_t*)(ws + 16 * MB);         // aliases xhi/xlo
  int*    rowmap = (int*)(ws + 31 * MB);          // 256 KB, past Oo's tail
  bf16_t* Wqhi = (bf16_t*)(ws + 32 * MB);
  bf16_t* Wqlo = (bf16_t*)(ws + 34 * MB);
  bf16_t* Wkb  = (bf16_t*)(ws + 36 * MB);
  bf16_t* Wvb  = (bf16_t*)(ws + 38 * MB);
  bf16_t* Wob  = (bf16_t*)(ws + 40 * MB);
  float*  norms = (float*)(ws + 42 * MB);
  int*    sel   = (int*)(ws + 42 * MB + (256u << 10));
  float*  Ol    = (float*)(ws + 42 * MB + (320u << 10));
  float*  Vmeanf = (float*)(ws + 42 * MB + (832u << 10));
  bf16_t* AOhi = Qhi;
  bf16_t* Khi = (bf16_t*)d_out;

  dim3 blk(256);
  prep_kernel<<<dim3(2048), blk, 0, stream>>>(x, Wq, Wk, Wv, Wo,
                                              xhi, xlo, Wqhi, Wqlo, Wkb, Wvb, Wob,
                                              Vmeanf);
  gemm_qkv<<<dim3(768), blk, 0, stream>>>(xhi, xlo, Wqhi, Wqlo, Wkb, Wvb,
                                          bq, bk, bv, Qhi, Khi, VThi, norms, Vmeanf);
  topk_kernel<<<dim3(32), dim3(1024), 0, stream>>>(norms, sel, rowmap);
  attn_kernel<<<dim3(32 * 4 * KSPLIT), blk, 0, stream>>>(Qhi, Khi, VThi, sel, Ol, Oo);
  fill_kernel<<<dim3(32, 32), blk, 0, stream>>>(Ol, Oo, rowmap, Vmeanf, AOhi);
  gemm_out<<<dim3(8, 64), blk, 0, stream>>>(AOhi, Wob, bo, out);
}